// Round 3
// baseline (149.930 us; speedup 1.0000x reference)
//
#include <hip/hip_runtime.h>
#include <hip/hip_bf16.h>

// CARNN: 9-step RNN (D=64) + projection to 300 actions, BATCH=65536.
// R3: 2 row-tiles per wave (32 rows) -> B-fragment reuse + 2 independent
// MFMA chains for ILP; v_rcp_f32 sigmoid; action ids prefetched; s-loop
// fully unrolled. Still barrier-free (hl wave-private in LDS).

#define BATCH   65536
#define SEQ     9
#define DMODEL  64
#define ANUM    300
#define RPB     128   // rows per block (4 waves x 32)
#define LSTR    72    // Hl row stride (bf16 elems)

// ws layout (bf16 element offsets)
#define WS_M    0        // 9*4096   M fragments [s][nt][kb][lane][8]
#define WS_W    36864    // 9*4096   W fragments
#define WS_OW   73728    // 5*4096   outw fragments [cc][nt][kb][lane][8]
#define WS_EMB  94208    // 301*64   bf16 emb table
#define WS_END  113472
#define WS_BSUM_BYTES (WS_END * 2)

typedef __attribute__((ext_vector_type(8))) short  bf16x8;
typedef __attribute__((ext_vector_type(4))) float  f32x4;

__device__ __forceinline__ unsigned short f2b(float f) {
    union { float f; unsigned int u; } x; x.f = f;
    unsigned int r = x.u + 0x7FFFu + ((x.u >> 16) & 1u);
    return (unsigned short)(r >> 16);
}

__device__ __forceinline__ float sigmoid_fast(float v) {
    return __builtin_amdgcn_rcpf(1.f + __expf(-v));   // v_exp + v_rcp
}

// ---------------- pre-pass: convert + pack (unchanged from R2) ----------------
#define PP_TOTAL (36864 + 20480 + 19264 + 576)

__global__ void prepack(const float* __restrict__ Mw, const float* __restrict__ Ww,
                        const float* __restrict__ outw, const float* __restrict__ emb,
                        const float* __restrict__ Mb, const float* __restrict__ Wb,
                        unsigned short* __restrict__ wsb, float* __restrict__ bsum)
{
    int t = blockIdx.x * 256 + threadIdx.x;
    if (t < 36864) {
        int j    = t & 7;
        int lane = (t >> 3) & 63;
        int kb   = (t >> 9) & 1;
        int nt   = (t >> 10) & 3;
        int s    = t >> 12;
        int nr   = nt * 16 + (lane & 15);
        int k    = kb * 32 + ((lane >> 4) << 3) + j;
        wsb[WS_M + t] = f2b(Mw[(s * DMODEL + nr) * DMODEL + k]);
        wsb[WS_W + t] = f2b(Ww[(s * DMODEL + nr) * DMODEL + k]);
        return;
    }
    t -= 36864;
    if (t < 20480) {
        int j    = t & 7;
        int lane = (t >> 3) & 63;
        int kb   = (t >> 9) & 1;
        int nt   = (t >> 10) & 3;
        int cc   = t >> 12;
        int col  = cc * 64 + nt * 16 + (lane & 15);
        int k    = kb * 32 + ((lane >> 4) << 3) + j;
        float v  = (col < ANUM) ? outw[col * DMODEL + k] : 0.f;
        wsb[WS_OW + t] = f2b(v);
        return;
    }
    t -= 20480;
    if (t < 19264) { wsb[WS_EMB + t] = f2b(emb[t]); return; }
    t -= 19264;
    if (t < 576)   { bsum[t] = Mb[t] + Wb[t]; }
}

// ---------------- main: barrier-free fused RNN, 2 tiles/wave ----------------
__global__ __launch_bounds__(256, 2)
void carnn_main(const int* __restrict__ acts,
                const unsigned short* __restrict__ wsb,
                const float* __restrict__ bsum,
                const float* __restrict__ outb,
                float* __restrict__ out)
{
    __shared__ unsigned short Hl[RPB * LSTR];

    const int tid  = threadIdx.x;
    const int lane = tid & 63;
    const int wv   = tid >> 6;
    const int lrow = lane & 15;
    const int quad = lane >> 4;
    const int m0   = wv * 32;                 // wave's private 32-row region

    const int bbase = blockIdx.x * RPB;

    // zero this wave's Hl region (wave-private; in-wave DS ordering suffices)
    for (int i = lane; i < 32 * LSTR; i += 64) Hl[m0 * LSTR + i] = 0;

    // prefetch action ids for both tiles (registers after unroll)
    const int brow0 = bbase + m0 + lrow;
    const int brow1 = brow0 + 16;
    int id0[SEQ], id1[SEQ];
    #pragma unroll
    for (int s = 0; s < SEQ; ++s) {
        id0[s] = acts[brow0 * SEQ + s];
        id1[s] = acts[brow1 * SEQ + s];
    }

    const unsigned short* Mp = wsb + WS_M;
    const unsigned short* Wp = wsb + WS_W;
    const unsigned short* Op = wsb + WS_OW;
    const unsigned short* Eb = wsb + WS_EMB;

    const int hrow0 = (m0 + lrow) * LSTR;          // tile0 A-row base
    const int hrow1 = (m0 + 16 + lrow) * LSTR;     // tile1 A-row base

    #pragma unroll
    for (int s = 0; s < SEQ; ++s) {
        const bf16x8* ex0 = (const bf16x8*)(Eb + id0[s] * DMODEL);
        const bf16x8* ex1 = (const bf16x8*)(Eb + id1[s] * DMODEL);
        bf16x8 ax0_0 = ex0[quad],     ax1_0 = ex0[4 + quad];
        bf16x8 ax0_1 = ex1[quad],     ax1_1 = ex1[4 + quad];
        bf16x8 ah0_0 = *(const bf16x8*)&Hl[hrow0 + quad * 8];
        bf16x8 ah1_0 = *(const bf16x8*)&Hl[hrow0 + 32 + quad * 8];
        bf16x8 ah0_1 = *(const bf16x8*)&Hl[hrow1 + quad * 8];
        bf16x8 ah1_1 = *(const bf16x8*)&Hl[hrow1 + 32 + quad * 8];

        #pragma unroll
        for (int nt = 0; nt < 4; ++nt) {
            const int fo = (s * 4 + nt) * 1024 + lane * 8;
            bf16x8 bm0 = *(const bf16x8*)&Mp[fo];
            bf16x8 bm1 = *(const bf16x8*)&Mp[fo + 512];
            bf16x8 bw0 = *(const bf16x8*)&Wp[fo];
            bf16x8 bw1 = *(const bf16x8*)&Wp[fo + 512];

            f32x4 acc0 = {0.f, 0.f, 0.f, 0.f};
            f32x4 acc1 = {0.f, 0.f, 0.f, 0.f};
            acc0 = __builtin_amdgcn_mfma_f32_16x16x32_bf16(ax0_0, bm0, acc0, 0, 0, 0);
            acc1 = __builtin_amdgcn_mfma_f32_16x16x32_bf16(ax0_1, bm0, acc1, 0, 0, 0);
            acc0 = __builtin_amdgcn_mfma_f32_16x16x32_bf16(ax1_0, bm1, acc0, 0, 0, 0);
            acc1 = __builtin_amdgcn_mfma_f32_16x16x32_bf16(ax1_1, bm1, acc1, 0, 0, 0);
            acc0 = __builtin_amdgcn_mfma_f32_16x16x32_bf16(ah0_0, bw0, acc0, 0, 0, 0);
            acc1 = __builtin_amdgcn_mfma_f32_16x16x32_bf16(ah0_1, bw0, acc1, 0, 0, 0);
            acc0 = __builtin_amdgcn_mfma_f32_16x16x32_bf16(ah1_0, bw1, acc0, 0, 0, 0);
            acc1 = __builtin_amdgcn_mfma_f32_16x16x32_bf16(ah1_1, bw1, acc1, 0, 0, 0);

            const int col  = nt * 16 + lrow;
            const float bias = bsum[s * DMODEL + col];
            const int wr0 = (m0 + quad * 4) * LSTR + col;
            #pragma unroll
            for (int r = 0; r < 4; ++r) {
                float h0 = sigmoid_fast(acc0[r] + bias);
                float h1 = sigmoid_fast(acc1[r] + bias);
                Hl[wr0 + r * LSTR] = f2b(h0);
                Hl[wr0 + (16 + r) * LSTR] = f2b(h1);
            }
        }
    }

    // ---- projection: out = hl @ outw^T + outb ----
    bf16x8 ah0_0 = *(const bf16x8*)&Hl[hrow0 + quad * 8];
    bf16x8 ah1_0 = *(const bf16x8*)&Hl[hrow0 + 32 + quad * 8];
    bf16x8 ah0_1 = *(const bf16x8*)&Hl[hrow1 + quad * 8];
    bf16x8 ah1_1 = *(const bf16x8*)&Hl[hrow1 + 32 + quad * 8];
    const int rowb0 = bbase + m0 + quad * 4;
    const int rowb1 = rowb0 + 16;

    #pragma unroll
    for (int cc = 0; cc < 5; ++cc) {
        #pragma unroll
        for (int nt = 0; nt < 4; ++nt) {
            const int fo = (cc * 4 + nt) * 1024 + lane * 8;
            bf16x8 b0 = *(const bf16x8*)&Op[fo];
            bf16x8 b1 = *(const bf16x8*)&Op[fo + 512];
            f32x4 acc0 = {0.f, 0.f, 0.f, 0.f};
            f32x4 acc1 = {0.f, 0.f, 0.f, 0.f};
            acc0 = __builtin_amdgcn_mfma_f32_16x16x32_bf16(ah0_0, b0, acc0, 0, 0, 0);
            acc1 = __builtin_amdgcn_mfma_f32_16x16x32_bf16(ah0_1, b0, acc1, 0, 0, 0);
            acc0 = __builtin_amdgcn_mfma_f32_16x16x32_bf16(ah1_0, b1, acc0, 0, 0, 0);
            acc1 = __builtin_amdgcn_mfma_f32_16x16x32_bf16(ah1_1, b1, acc1, 0, 0, 0);

            const int col = cc * 64 + nt * 16 + lrow;
            if (col < ANUM) {
                const float bias = outb[col];
                #pragma unroll
                for (int r = 0; r < 4; ++r) {
                    out[(rowb0 + r) * ANUM + col] = acc0[r] + bias;
                    out[(rowb1 + r) * ANUM + col] = acc1[r] + bias;
                }
            }
        }
    }
}

extern "C" void kernel_launch(void* const* d_in, const int* in_sizes, int n_in,
                              void* d_out, int out_size, void* d_ws, size_t ws_size,
                              hipStream_t stream) {
    const int*   acts = (const int*)  d_in[0];
    const float* emb  = (const float*)d_in[1];
    const float* Mw   = (const float*)d_in[2];
    const float* Mb   = (const float*)d_in[3];
    const float* Ww   = (const float*)d_in[4];
    const float* Wb   = (const float*)d_in[5];
    const float* outw = (const float*)d_in[6];
    const float* outb = (const float*)d_in[7];
    float* out = (float*)d_out;
    (void)in_sizes; (void)n_in; (void)ws_size; (void)out_size;

    unsigned short* wsb = (unsigned short*)d_ws;
    float* bsum = (float*)((char*)d_ws + WS_BSUM_BYTES);

    prepack<<<(PP_TOTAL + 255) / 256, 256, 0, stream>>>(Mw, Ww, outw, emb, Mb, Wb, wsb, bsum);
    carnn_main<<<BATCH / RPB, 256, 0, stream>>>(acts, wsb, bsum, outb, out);
}

// Round 4
// 139.357 us; speedup vs baseline: 1.0759x; 1.0759x over previous
//
#include <hip/hip_runtime.h>
#include <hip/hip_bf16.h>

// CARNN: 9-step RNN (D=64) + projection to 300 actions, BATCH=65536.
// R4: split-N cooperation — 2 waves co-own one 16-row tile (each does 2 of 4
// nt column-tiles). Double-buffered H in LDS, 1 barrier/step. 128-thread
// blocks, grid 4096 -> 32 waves/CU occupancy cap (was grid-capped at 16).

#define BATCH   65536
#define SEQ     9
#define DMODEL  64
#define ANUM    300
#define LSTR    72    // H row stride (bf16 elems)

// ws layout (bf16 element offsets) — packed by prepack
#define WS_M    0        // 9*4096   M fragments [s][nt][kb][lane][8]
#define WS_W    36864    // 9*4096   W fragments
#define WS_OW   73728    // 5*4096   outw fragments [cc][nt][kb][lane][8]
#define WS_EMB  94208    // 301*64   bf16 emb table
#define WS_END  113472
#define WS_BSUM_BYTES (WS_END * 2)

typedef __attribute__((ext_vector_type(8))) short  bf16x8;
typedef __attribute__((ext_vector_type(4))) float  f32x4;

__device__ __forceinline__ unsigned short f2b(float f) {
    union { float f; unsigned int u; } x; x.f = f;
    unsigned int r = x.u + 0x7FFFu + ((x.u >> 16) & 1u);
    return (unsigned short)(r >> 16);
}

__device__ __forceinline__ float sigmoid_fast(float v) {
    return __builtin_amdgcn_rcpf(1.f + __expf(-v));
}

// ---------------- pre-pass: convert + pack (unchanged) ----------------
#define PP_TOTAL (36864 + 20480 + 19264 + 576)

__global__ void prepack(const float* __restrict__ Mw, const float* __restrict__ Ww,
                        const float* __restrict__ outw, const float* __restrict__ emb,
                        const float* __restrict__ Mb, const float* __restrict__ Wb,
                        unsigned short* __restrict__ wsb, float* __restrict__ bsum)
{
    int t = blockIdx.x * 256 + threadIdx.x;
    if (t < 36864) {
        int j    = t & 7;
        int lane = (t >> 3) & 63;
        int kb   = (t >> 9) & 1;
        int nt   = (t >> 10) & 3;
        int s    = t >> 12;
        int nr   = nt * 16 + (lane & 15);
        int k    = kb * 32 + ((lane >> 4) << 3) + j;
        wsb[WS_M + t] = f2b(Mw[(s * DMODEL + nr) * DMODEL + k]);
        wsb[WS_W + t] = f2b(Ww[(s * DMODEL + nr) * DMODEL + k]);
        return;
    }
    t -= 36864;
    if (t < 20480) {
        int j    = t & 7;
        int lane = (t >> 3) & 63;
        int kb   = (t >> 9) & 1;
        int nt   = (t >> 10) & 3;
        int cc   = t >> 12;
        int col  = cc * 64 + nt * 16 + (lane & 15);
        int k    = kb * 32 + ((lane >> 4) << 3) + j;
        float v  = (col < ANUM) ? outw[col * DMODEL + k] : 0.f;
        wsb[WS_OW + t] = f2b(v);
        return;
    }
    t -= 20480;
    if (t < 19264) { wsb[WS_EMB + t] = f2b(emb[t]); return; }
    t -= 19264;
    if (t < 576)   { bsum[t] = Mb[t] + Wb[t]; }
}

// ---------------- main: 2 waves per 16-row tile, dbuf H, 1 barrier/step ----
__global__ __launch_bounds__(128, 8)
void carnn_main(const int* __restrict__ acts,
                const unsigned short* __restrict__ wsb,
                const float* __restrict__ bsum,
                const float* __restrict__ outb,
                float* __restrict__ out)
{
    __shared__ unsigned short Hl[2][16 * LSTR];   // double-buffered team H

    const int tid  = threadIdx.x;
    const int lane = tid & 63;
    const int w01  = tid >> 6;         // wave in team: 0 -> nt 0,1 ; 1 -> nt 2,3
    const int lrow = lane & 15;
    const int quad = lane >> 4;

    const int brow = blockIdx.x * 16 + lrow;   // this lane's A-row (batch idx)

    // zero read-buffer 0 cooperatively
    for (int i = tid; i < 16 * LSTR; i += 128) Hl[0][i] = 0;
    __syncthreads();

    const unsigned short* Mp = wsb + WS_M;
    const unsigned short* Wp = wsb + WS_W;
    const unsigned short* Op = wsb + WS_OW;
    const unsigned short* Eb = wsb + WS_EMB;

    const int hoff = lrow * LSTR + quad * 8;   // A-frag read offset within buf

    #pragma unroll
    for (int s = 0; s < SEQ; ++s) {
        const int rb = s & 1, wb = rb ^ 1;

        // H A-frags (previous step) — wave-shared rows, read-only this step
        bf16x8 ah0 = *(const bf16x8*)&Hl[rb][hoff];
        bf16x8 ah1 = *(const bf16x8*)&Hl[rb][hoff + 32];

        // X A-frags from packed bf16 emb table
        int id = acts[brow * SEQ + s];
        const bf16x8* ex = (const bf16x8*)(Eb + id * DMODEL);
        bf16x8 ax0 = ex[quad];
        bf16x8 ax1 = ex[4 + quad];

        #pragma unroll
        for (int ntl = 0; ntl < 2; ++ntl) {
            const int nt = w01 * 2 + ntl;
            const int fo = (s * 4 + nt) * 1024 + lane * 8;
            bf16x8 bm0 = *(const bf16x8*)&Mp[fo];
            bf16x8 bm1 = *(const bf16x8*)&Mp[fo + 512];
            bf16x8 bw0 = *(const bf16x8*)&Wp[fo];
            bf16x8 bw1 = *(const bf16x8*)&Wp[fo + 512];

            f32x4 acc = {0.f, 0.f, 0.f, 0.f};
            acc = __builtin_amdgcn_mfma_f32_16x16x32_bf16(ax0, bm0, acc, 0, 0, 0);
            acc = __builtin_amdgcn_mfma_f32_16x16x32_bf16(ax1, bm1, acc, 0, 0, 0);
            acc = __builtin_amdgcn_mfma_f32_16x16x32_bf16(ah0, bw0, acc, 0, 0, 0);
            acc = __builtin_amdgcn_mfma_f32_16x16x32_bf16(ah1, bw1, acc, 0, 0, 0);

            const int col  = nt * 16 + lrow;
            const float bias = bsum[s * DMODEL + col];
            const int wr = (quad * 4) * LSTR + col;
            #pragma unroll
            for (int r = 0; r < 4; ++r) {
                float h = sigmoid_fast(acc[r] + bias);
                Hl[wb][wr + r * LSTR] = f2b(h);
            }
        }
        __syncthreads();   // publish H(s+1) before anyone reads it
    }

    // ---- projection: final H is in buf 1 (last write: s=8 -> wb=1) ----
    bf16x8 ah0 = *(const bf16x8*)&Hl[1][hoff];
    bf16x8 ah1 = *(const bf16x8*)&Hl[1][hoff + 32];
    const int rowb = blockIdx.x * 16 + quad * 4;

    #pragma unroll
    for (int cc = 0; cc < 5; ++cc) {
        #pragma unroll
        for (int ntl = 0; ntl < 2; ++ntl) {
            const int nt = w01 * 2 + ntl;
            const int fo = (cc * 4 + nt) * 1024 + lane * 8;
            bf16x8 b0 = *(const bf16x8*)&Op[fo];
            bf16x8 b1 = *(const bf16x8*)&Op[fo + 512];
            f32x4 acc = {0.f, 0.f, 0.f, 0.f};
            acc = __builtin_amdgcn_mfma_f32_16x16x32_bf16(ah0, b0, acc, 0, 0, 0);
            acc = __builtin_amdgcn_mfma_f32_16x16x32_bf16(ah1, b1, acc, 0, 0, 0);

            const int col = cc * 64 + nt * 16 + lrow;
            if (col < ANUM) {
                const float bias = outb[col];
                #pragma unroll
                for (int r = 0; r < 4; ++r)
                    out[(rowb + r) * ANUM + col] = acc[r] + bias;
            }
        }
    }
}

extern "C" void kernel_launch(void* const* d_in, const int* in_sizes, int n_in,
                              void* d_out, int out_size, void* d_ws, size_t ws_size,
                              hipStream_t stream) {
    const int*   acts = (const int*)  d_in[0];
    const float* emb  = (const float*)d_in[1];
    const float* Mw   = (const float*)d_in[2];
    const float* Mb   = (const float*)d_in[3];
    const float* Ww   = (const float*)d_in[4];
    const float* Wb   = (const float*)d_in[5];
    const float* outw = (const float*)d_in[6];
    const float* outb = (const float*)d_in[7];
    float* out = (float*)d_out;
    (void)in_sizes; (void)n_in; (void)ws_size; (void)out_size;

    unsigned short* wsb = (unsigned short*)d_ws;
    float* bsum = (float*)((char*)d_ws + WS_BSUM_BYTES);

    prepack<<<(PP_TOTAL + 255) / 256, 256, 0, stream>>>(Mw, Ww, outw, emb, Mb, Wb, wsb, bsum);
    carnn_main<<<BATCH / 16, 128, 0, stream>>>(acts, wsb, bsum, outb, out);
}

// Round 5
// 124.231 us; speedup vs baseline: 1.2069x; 1.1218x over previous
//
#include <hip/hip_runtime.h>
#include <hip/hip_bf16.h>

// CARNN: 9-step RNN (D=64) + projection to 300 actions, BATCH=65536.
// R5: weights staged per-block into LDS via global_load_lds (16B), double
// buffered, 1 barrier/step. 1024-thr blocks = 16 waves = 128 rows (8 split-N
// teams), grid 512 = 2 blocks/CU = 32 waves/CU. Kills the L2 hot-line
// contention from all waves re-reading the same fragments.

#define SEQ     9
#define DMODEL  64
#define ANUM    300
#define RPB     128   // rows per block
#define LSTR    72    // H row stride (bf16 elems)

// ws layout (bf16 element offsets)
#define WS_MW   0        // 9*8192: per step [kind(M=0,W=1)][nt][kb][lane][8]
#define WS_OW   73728    // 5*4096: [cc][nt][kb][lane][8]
#define WS_EMB  94208    // 301*64 bf16 emb table
#define WS_END  113472
#define WS_BSUM_BYTES (WS_END * 2)

typedef __attribute__((ext_vector_type(8))) short  bf16x8;
typedef __attribute__((ext_vector_type(4))) float  f32x4;

__device__ __forceinline__ unsigned short f2b(float f) {
    union { float f; unsigned int u; } x; x.f = f;
    unsigned int r = x.u + 0x7FFFu + ((x.u >> 16) & 1u);
    return (unsigned short)(r >> 16);
}

__device__ __forceinline__ float sigmoid_fast(float v) {
    return __builtin_amdgcn_rcpf(1.f + __expf(-v));
}

// async global->LDS, 16 B per lane; lds base must be wave-uniform
__device__ __forceinline__ void async16(const unsigned short* g, unsigned short* l) {
    __builtin_amdgcn_global_load_lds(
        (const __attribute__((address_space(1))) unsigned int*)g,
        (__attribute__((address_space(3))) unsigned int*)l, 16, 0, 0);
}

// ---------------- pre-pass: convert + pack ----------------
#define PP_TOTAL (73728 + 20480 + 19264 + 576)

__global__ void prepack(const float* __restrict__ Mw, const float* __restrict__ Ww,
                        const float* __restrict__ outw, const float* __restrict__ emb,
                        const float* __restrict__ Mb, const float* __restrict__ Wb,
                        unsigned short* __restrict__ wsb, float* __restrict__ bsum)
{
    int t = blockIdx.x * 256 + threadIdx.x;
    if (t < 73728) {                       // M+W, step-major 16KB blocks
        int s    = t >> 13;
        int r    = t & 8191;
        int kind = r >> 12;
        int f    = r & 4095;
        int nt   = f >> 10;
        int kb   = (f >> 9) & 1;
        int lane = (f >> 3) & 63;
        int j    = f & 7;
        int nr   = nt * 16 + (lane & 15);
        int k    = kb * 32 + ((lane >> 4) << 3) + j;
        const float* src = kind ? Ww : Mw;
        wsb[WS_MW + t] = f2b(src[(s * DMODEL + nr) * DMODEL + k]);
        return;
    }
    t -= 73728;
    if (t < 20480) {                       // outw fragments
        int j    = t & 7;
        int lane = (t >> 3) & 63;
        int kb   = (t >> 9) & 1;
        int nt   = (t >> 10) & 3;
        int cc   = t >> 12;
        int col  = cc * 64 + nt * 16 + (lane & 15);
        int k    = kb * 32 + ((lane >> 4) << 3) + j;
        float v  = (col < ANUM) ? outw[col * DMODEL + k] : 0.f;
        wsb[WS_OW + t] = f2b(v);
        return;
    }
    t -= 20480;
    if (t < 19264) { wsb[WS_EMB + t] = f2b(emb[t]); return; }
    t -= 19264;
    if (t < 576)   { bsum[t] = Mb[t] + Wb[t]; }
}

// ---------------- main ----------------
__global__ __launch_bounds__(1024, 8)
void carnn_main(const int* __restrict__ acts,
                const unsigned short* __restrict__ wsb,
                const float* __restrict__ bsum,
                const float* __restrict__ outb,
                float* __restrict__ out)
{
    __shared__ unsigned short Wf[2][8192];        // 2 x 16 KB weight frags
    __shared__ unsigned short Hl[2][RPB * LSTR];  // 2 x 18 KB hidden state

    const int tid  = threadIdx.x;
    const int lane = tid & 63;
    const int wv   = tid >> 6;         // 0..15
    const int team = wv >> 1;          // 0..7 (16 rows each)
    const int half = wv & 1;           // nt pair: {0,1} or {2,3}
    const int lrow = lane & 15;
    const int quad = lane >> 4;

    const int brow = blockIdx.x * RPB + team * 16 + lrow;
    const int hoff = (team * 16 + lrow) * LSTR + quad * 8;

    // zero H[0]
    for (int i = tid; i < RPB * LSTR; i += 1024) Hl[0][i] = 0;
    // stage step-0 weights (16 KB: one 16B async per thread)
    async16(wsb + WS_MW + tid * 8, &Wf[0][wv * 512]);

    const unsigned short* Eb = wsb + WS_EMB;
    int idcur = acts[brow * SEQ];      // step-0 action id

    __syncthreads();                   // drains vmcnt -> stage-0 complete

    #pragma unroll
    for (int s = 0; s < SEQ; ++s) {
        const int rb = s & 1, wb = rb ^ 1;

        // X fragments (direct gather from bf16 emb table)
        const bf16x8* ex = (const bf16x8*)(Eb + idcur * DMODEL);
        bf16x8 ax0 = ex[quad];
        bf16x8 ax1 = ex[4 + quad];

        // prefetch next action id + next weight block (or proj chunk 0)
        if (s + 1 < SEQ) {
            idcur = acts[brow * SEQ + s + 1];
            async16(wsb + WS_MW + (s + 1) * 8192 + tid * 8, &Wf[wb][wv * 512]);
        } else {
            if (wv < 8) async16(wsb + WS_OW + tid * 8, &Wf[wb][wv * 512]);
        }

        // H fragments (previous step)
        bf16x8 ah0 = *(const bf16x8*)&Hl[rb][hoff];
        bf16x8 ah1 = *(const bf16x8*)&Hl[rb][hoff + 32];

        #pragma unroll
        for (int ntl = 0; ntl < 2; ++ntl) {
            const int nt = half * 2 + ntl;
            const unsigned short* Mf  = &Wf[rb][nt * 1024 + lane * 8];
            const unsigned short* Wfp = &Wf[rb][4096 + nt * 1024 + lane * 8];
            bf16x8 bm0 = *(const bf16x8*)Mf;
            bf16x8 bm1 = *(const bf16x8*)(Mf + 512);
            bf16x8 bw0 = *(const bf16x8*)Wfp;
            bf16x8 bw1 = *(const bf16x8*)(Wfp + 512);

            f32x4 acc = {0.f, 0.f, 0.f, 0.f};
            acc = __builtin_amdgcn_mfma_f32_16x16x32_bf16(ax0, bm0, acc, 0, 0, 0);
            acc = __builtin_amdgcn_mfma_f32_16x16x32_bf16(ax1, bm1, acc, 0, 0, 0);
            acc = __builtin_amdgcn_mfma_f32_16x16x32_bf16(ah0, bw0, acc, 0, 0, 0);
            acc = __builtin_amdgcn_mfma_f32_16x16x32_bf16(ah1, bw1, acc, 0, 0, 0);

            const int col  = nt * 16 + lrow;
            const float bias = bsum[s * DMODEL + col];
            const int wr = (team * 16 + quad * 4) * LSTR + col;
            #pragma unroll
            for (int r = 0; r < 4; ++r) {
                float h = sigmoid_fast(acc[r] + bias);
                Hl[wb][wr + r * LSTR] = f2b(h);
            }
        }
        __syncthreads();   // publishes H(s+1) AND completes weight prefetch
    }

    // ---- projection: final H in Hl[1]; Op chunk 0 already in Wf[1] ----
    bf16x8 ah0 = *(const bf16x8*)&Hl[1][hoff];
    bf16x8 ah1 = *(const bf16x8*)&Hl[1][hoff + 32];
    const int rowb = blockIdx.x * RPB + team * 16 + quad * 4;

    #pragma unroll
    for (int cc = 0; cc < 5; ++cc) {
        const int rbuf = (cc + 1) & 1;     // cc0 reads Wf[1]
        const int wbuf = rbuf ^ 1;
        if (cc + 1 < 5 && wv < 8)
            async16(wsb + WS_OW + (cc + 1) * 4096 + tid * 8, &Wf[wbuf][wv * 512]);

        #pragma unroll
        for (int ntl = 0; ntl < 2; ++ntl) {
            const int nt = half * 2 + ntl;
            const unsigned short* Of = &Wf[rbuf][nt * 1024 + lane * 8];
            bf16x8 b0 = *(const bf16x8*)Of;
            bf16x8 b1 = *(const bf16x8*)(Of + 512);
            f32x4 acc = {0.f, 0.f, 0.f, 0.f};
            acc = __builtin_amdgcn_mfma_f32_16x16x32_bf16(ah0, b0, acc, 0, 0, 0);
            acc = __builtin_amdgcn_mfma_f32_16x16x32_bf16(ah1, b1, acc, 0, 0, 0);

            const int col = cc * 64 + nt * 16 + lrow;
            if (col < ANUM) {
                const float bias = outb[col];
                #pragma unroll
                for (int r = 0; r < 4; ++r)
                    out[(rowb + r) * ANUM + col] = acc[r] + bias;
            }
        }
        if (cc + 1 < 5) __syncthreads();   // before restaging Wf
    }
}

extern "C" void kernel_launch(void* const* d_in, const int* in_sizes, int n_in,
                              void* d_out, int out_size, void* d_ws, size_t ws_size,
                              hipStream_t stream) {
    const int*   acts = (const int*)  d_in[0];
    const float* emb  = (const float*)d_in[1];
    const float* Mw   = (const float*)d_in[2];
    const float* Mb   = (const float*)d_in[3];
    const float* Ww   = (const float*)d_in[4];
    const float* Wb   = (const float*)d_in[5];
    const float* outw = (const float*)d_in[6];
    const float* outb = (const float*)d_in[7];
    float* out = (float*)d_out;
    (void)in_sizes; (void)n_in; (void)ws_size; (void)out_size;

    unsigned short* wsb = (unsigned short*)d_ws;
    float* bsum = (float*)((char*)d_ws + WS_BSUM_BYTES);

    prepack<<<(PP_TOTAL + 255) / 256, 256, 0, stream>>>(Mw, Ww, outw, emb, Mb, Wb, wsb, bsum);
    carnn_main<<<65536 / RPB, 1024, 0, stream>>>(acts, wsb, bsum, outb, out);
}